// Round 1
// baseline (113.153 us; speedup 1.0000x reference)
//
#include <hip/hip_runtime.h>
#include <hip/hip_bf16.h>
#include <stdint.h>

#define E_  1024
#define H_  16
#define D_  64
#define K_  8
#define B_  4
#define S_  2048
#define KH_ 128   // K_*H_

typedef __attribute__((ext_vector_type(8))) short   short8;
typedef __attribute__((ext_vector_type(8))) ushort  ushort8;
typedef __attribute__((ext_vector_type(4))) float   f32x4;

__device__ __forceinline__ ushort f2bf(float x){
  union { float f; uint32_t u; } v; v.f = x;
  return (ushort)((v.u + 0x7FFFu + ((v.u >> 16) & 1u)) >> 16);
}

// ---------------- T0: rep (B,S,E) f32 -> repT (B,E,S) bf16 ----------------
__global__ __launch_bounds__(256) void t0_repT(const float* __restrict__ rep,
                                               ushort* __restrict__ repT){
  __shared__ ushort tile[64][65];
  int bid = blockIdx.x;
  int et = bid & 15;          // E/64
  int st = (bid >> 4) & 31;   // S/64
  int b  = bid >> 9;
  int t = threadIdx.x;
  int s_l = t >> 2;
  int e0  = (t & 3) * 16;
  const float* src = rep + ((size_t)(b*S_) + st*64 + s_l)*E_ + et*64 + e0;
  #pragma unroll
  for (int q = 0; q < 4; q++){
    float4 v = *(const float4*)(src + q*4);
    tile[s_l][e0+q*4+0] = f2bf(v.x);
    tile[s_l][e0+q*4+1] = f2bf(v.y);
    tile[s_l][e0+q*4+2] = f2bf(v.z);
    tile[s_l][e0+q*4+3] = f2bf(v.w);
  }
  __syncthreads();
  int e_l = t >> 2;
  int sc  = (t & 3) * 16;
  alignas(16) ushort tmp[16];
  #pragma unroll
  for (int i = 0; i < 16; i++) tmp[i] = tile[sc+i][e_l];
  ushort* dst = repT + ((size_t)(b*E_) + et*64 + e_l)*S_ + st*64 + sc;
  *(uint4*)dst       = *(const uint4*)tmp;
  *(uint4*)(dst + 8) = *(const uint4*)(tmp + 8);
}

// ---------------- K1: qs[k,f] = (queries[k,:]·Wq[k,f,:] + bq)*0.125 -------
__global__ __launch_bounds__(256) void k1_qs(const float* __restrict__ queries,
                                             const float* __restrict__ Wq,
                                             const float* __restrict__ bq,
                                             float* __restrict__ qs){
  int gw = (blockIdx.x * 256 + threadIdx.x) >> 6;
  int lane = threadIdx.x & 63;
  int k = gw >> 10, f = gw & 1023;
  const float* wrow = Wq + ((size_t)(k*E_) + f)*E_;
  const float* qrow = queries + k*E_;
  float acc = 0.f;
  #pragma unroll
  for (int j = 0; j < 4; j++){
    int e = (j*64 + lane)*4;
    float4 w = *(const float4*)(wrow + e);
    float4 q = *(const float4*)(qrow + e);
    acc += w.x*q.x + w.y*q.y + w.z*q.z + w.w*q.w;
  }
  #pragma unroll
  for (int off = 32; off; off >>= 1) acc += __shfl_down(acc, off);
  if (lane == 0) qs[k*E_ + f] = (acc + bq[k*E_ + f]) * 0.125f;
}

// ---------------- K2: qk[k,h,e] (bf16) and qb[k,h] ------------------------
__global__ __launch_bounds__(256) void k2_qk(const float* __restrict__ qs,
                                             const float* __restrict__ Wk,
                                             const float* __restrict__ bk,
                                             ushort* __restrict__ qkb,
                                             float* __restrict__ qb){
  int bid = blockIdx.x;
  int half = bid & 1;
  int kh = bid >> 1;
  int k = kh >> 4, h = kh & 15;
  __shared__ float qsh[64];
  int t = threadIdx.x;
  if (t < 64) qsh[t] = qs[k*E_ + h*64 + t];
  __syncthreads();
  int e = half*512 + t;
  const float* wbase = Wk + ((size_t)(k*E_) + h*64)*E_;
  float a0 = 0.f, a1 = 0.f;
  for (int d = 0; d < 64; d++){
    float q = qsh[d];
    a0 += q * wbase[(size_t)d*E_ + e];
    a1 += q * wbase[(size_t)d*E_ + e + 256];
  }
  qkb[kh*E_ + e]       = f2bf(a0);
  qkb[kh*E_ + e + 256] = f2bf(a1);
  if (half == 0 && t == 0){
    float s = 0.f;
    for (int d = 0; d < 64; d++) s += qsh[d] * bk[k*E_ + h*64 + d];
    qb[kh] = s;
  }
}

// ---------------- K3: scores[b,kh,s] = rep·qk + qb + mask (MFMA) ----------
__global__ __launch_bounds__(256) void k3_scores(const float* __restrict__ rep,
                                                 const ushort* __restrict__ qkb,
                                                 const float* __restrict__ qb,
                                                 const float* __restrict__ mask,
                                                 float* __restrict__ scores){
  __shared__ ushort repL[64][40];   // 32 cols used, padded rows (80B, 16B-aligned)
  __shared__ ushort qkL[128][40];
  __shared__ float  scL[128][68];   // [kh][s_local], 272B rows
  int bid = blockIdx.x;
  int st = bid & 31;
  int b  = bid >> 5;
  int t = threadIdx.x;
  int wv = t >> 6, lane = t & 63;
  f32x4 acc[4][2];
  #pragma unroll
  for (int mt = 0; mt < 4; mt++)
    #pragma unroll
    for (int nn = 0; nn < 2; nn++) acc[mt][nn] = (f32x4){0.f,0.f,0.f,0.f};

  int s_l = t >> 2, qq = t & 3;     // rep staging role
  int kh_l = t >> 1, hf = t & 1;    // qk staging role
  const float* repRow = rep + ((size_t)(b*S_) + st*64 + s_l)*E_;

  for (int ke = 0; ke < 32; ke++){
    {
      float4 v0 = *(const float4*)(repRow + ke*32 + qq*8);
      float4 v1 = *(const float4*)(repRow + ke*32 + qq*8 + 4);
      ushort8 u;
      u[0]=f2bf(v0.x); u[1]=f2bf(v0.y); u[2]=f2bf(v0.z); u[3]=f2bf(v0.w);
      u[4]=f2bf(v1.x); u[5]=f2bf(v1.y); u[6]=f2bf(v1.z); u[7]=f2bf(v1.w);
      *(ushort8*)&repL[s_l][qq*8] = u;
    }
    {
      const ushort* qrow = qkb + (size_t)kh_l*E_ + ke*32 + hf*16;
      uint4 u0 = *(const uint4*)qrow;
      uint4 u1 = *(const uint4*)(qrow + 8);
      *(uint4*)&qkL[kh_l][hf*16]     = u0;
      *(uint4*)&qkL[kh_l][hf*16 + 8] = u1;
    }
    __syncthreads();
    short8 af[4];
    #pragma unroll
    for (int mt = 0; mt < 4; mt++)
      af[mt] = *(const short8*)&repL[mt*16 + (lane&15)][(lane>>4)*8];
    #pragma unroll
    for (int nn = 0; nn < 2; nn++){
      int nt = wv*2 + nn;
      short8 bf = *(const short8*)&qkL[nt*16 + (lane&15)][(lane>>4)*8];
      #pragma unroll
      for (int mt = 0; mt < 4; mt++)
        acc[mt][nn] = __builtin_amdgcn_mfma_f32_16x16x32_bf16(af[mt], bf, acc[mt][nn], 0,0,0);
    }
    __syncthreads();
  }
  #pragma unroll
  for (int nn = 0; nn < 2; nn++){
    int nt = wv*2 + nn;
    #pragma unroll
    for (int mt = 0; mt < 4; mt++)
      #pragma unroll
      for (int r = 0; r < 4; r++)
        scL[nt*16 + (lane&15)][mt*16 + (lane>>4)*4 + r] = acc[mt][nn][r];
  }
  __syncthreads();
  int kh = t >> 1, sh = (t & 1) * 32;
  float qbv = qb[kh];
  const float* mrow = mask + b*S_ + st*64 + sh;
  float* orow = scores + ((size_t)(b*KH_) + kh)*S_ + st*64 + sh;
  #pragma unroll
  for (int i = 0; i < 32; i += 4){
    float4 v = *(const float4*)&scL[kh][sh + i];
    float4 m = *(const float4*)(mrow + i);
    v.x += qbv + m.x; v.y += qbv + m.y; v.z += qbv + m.z; v.w += qbv + m.w;
    *(float4*)(orow + i) = v;
  }
}

// ---------------- K4: row softmax -> probs bf16 ---------------------------
__global__ __launch_bounds__(256) void k4_softmax(const float* __restrict__ scores,
                                                  ushort* __restrict__ probs){
  __shared__ float red[4];
  int row = blockIdx.x;
  int t = threadIdx.x, wv = t >> 6, lane = t & 63;
  const float* x = scores + (size_t)row * S_;
  float v[8];
  *(float4*)(v)   = *(const float4*)(x + t*8);
  *(float4*)(v+4) = *(const float4*)(x + t*8 + 4);
  float m = v[0];
  #pragma unroll
  for (int i = 1; i < 8; i++) m = fmaxf(m, v[i]);
  #pragma unroll
  for (int off = 32; off; off >>= 1) m = fmaxf(m, __shfl_down(m, off));
  if (lane == 0) red[wv] = m;
  __syncthreads();
  float M = fmaxf(fmaxf(red[0], red[1]), fmaxf(red[2], red[3]));
  __syncthreads();
  float s = 0.f;
  #pragma unroll
  for (int i = 0; i < 8; i++){ v[i] = __expf(v[i] - M); s += v[i]; }
  #pragma unroll
  for (int off = 32; off; off >>= 1) s += __shfl_down(s, off);
  if (lane == 0) red[wv] = s;
  __syncthreads();
  float inv = 1.0f / (red[0] + red[1] + red[2] + red[3]);
  ushort8 o;
  #pragma unroll
  for (int i = 0; i < 8; i++) o[i] = f2bf(v[i] * inv);
  *(ushort8*)(probs + (size_t)row*S_ + t*8) = o;
}

// ---------------- K5: wrep[b,kh,e] = probs·rep  (MFMA, repT layout) -------
__global__ __launch_bounds__(256) void k5_wrep(const ushort* __restrict__ probs,
                                               const ushort* __restrict__ repT,
                                               float* __restrict__ wrep){
  int bid = blockIdx.x;
  int et = bid & 63;
  int b  = bid >> 6;
  int t = threadIdx.x, wv = t >> 6, lane = t & 63;
  int e0 = et*16;
  const ushort* A  = probs + (size_t)(b*KH_)*S_;
  const ushort* Bp = repT + ((size_t)(b*E_) + e0 + (lane&15))*S_;
  int m0 = wv*32 + (lane&15);
  int soff = (lane>>4)*8;
  const ushort* a0p = A + (size_t)m0*S_;
  const ushort* a1p = A + (size_t)(m0+16)*S_;
  f32x4 c0 = {0.f,0.f,0.f,0.f}, c1 = {0.f,0.f,0.f,0.f};
  for (int ks = 0; ks < 64; ks++){
    int s = ks*32 + soff;
    short8 a0 = *(const short8*)(a0p + s);
    short8 a1 = *(const short8*)(a1p + s);
    short8 bb = *(const short8*)(Bp + s);
    c0 = __builtin_amdgcn_mfma_f32_16x16x32_bf16(a0, bb, c0, 0,0,0);
    c1 = __builtin_amdgcn_mfma_f32_16x16x32_bf16(a1, bb, c1, 0,0,0);
  }
  int eo = e0 + (lane&15);
  int khbase = wv*32 + (lane>>4)*4;
  #pragma unroll
  for (int r = 0; r < 4; r++){
    wrep[((size_t)(b*KH_) + khbase + r)*E_ + eo]      = c0[r];
    wrep[((size_t)(b*KH_) + khbase + 16 + r)*E_ + eo] = c1[r];
  }
}

// ---------------- K6: ctx[k,b,f] = wrep[b,kh(f),:]·Wv[k,f,:] + bv ---------
__global__ __launch_bounds__(256) void k6_ctx(const float* __restrict__ wrep,
                                              const float* __restrict__ Wv,
                                              const float* __restrict__ bv,
                                              float* __restrict__ ctx){
  int gw = (blockIdx.x*256 + threadIdx.x) >> 6;
  int lane = threadIdx.x & 63;
  int k = gw >> 10, f = gw & 1023;
  int h = f >> 6;
  const float* wrow = Wv + ((size_t)(k*E_) + f)*E_;
  const float* x0 = wrep + ((size_t)(0*KH_) + k*16 + h)*E_;
  const float* x1 = wrep + ((size_t)(1*KH_) + k*16 + h)*E_;
  const float* x2 = wrep + ((size_t)(2*KH_) + k*16 + h)*E_;
  const float* x3 = wrep + ((size_t)(3*KH_) + k*16 + h)*E_;
  float a0=0.f, a1=0.f, a2=0.f, a3=0.f;
  #pragma unroll
  for (int j = 0; j < 4; j++){
    int e = (j*64 + lane)*4;
    float4 w = *(const float4*)(wrow + e);
    float4 p;
    p = *(const float4*)(x0+e); a0 += w.x*p.x + w.y*p.y + w.z*p.z + w.w*p.w;
    p = *(const float4*)(x1+e); a1 += w.x*p.x + w.y*p.y + w.z*p.z + w.w*p.w;
    p = *(const float4*)(x2+e); a2 += w.x*p.x + w.y*p.y + w.z*p.z + w.w*p.w;
    p = *(const float4*)(x3+e); a3 += w.x*p.x + w.y*p.y + w.z*p.z + w.w*p.w;
  }
  #pragma unroll
  for (int off = 32; off; off >>= 1){
    a0 += __shfl_down(a0, off); a1 += __shfl_down(a1, off);
    a2 += __shfl_down(a2, off); a3 += __shfl_down(a3, off);
  }
  if (lane == 0){
    float bvv = bv[k*E_ + f];
    ctx[((size_t)(k*B_) + 0)*E_ + f] = a0 + bvv;
    ctx[((size_t)(k*B_) + 1)*E_ + f] = a1 + bvv;
    ctx[((size_t)(k*B_) + 2)*E_ + f] = a2 + bvv;
    ctx[((size_t)(k*B_) + 3)*E_ + f] = a3 + bvv;
  }
}

// ---------------- K7/K8: out[(k,b),f] = in[(k,b),:]·W[k,f,:] + bias -------
__global__ __launch_bounds__(256) void gemv_kb(const float* __restrict__ in,
                                               const float* __restrict__ W,
                                               const float* __restrict__ bias,
                                               float* __restrict__ outp){
  int gw = (blockIdx.x*256 + threadIdx.x) >> 6;
  int lane = threadIdx.x & 63;
  int k = gw >> 10, f = gw & 1023;
  const float* wrow = W + ((size_t)(k*E_) + f)*E_;
  const float* x0 = in + ((size_t)(k*B_) + 0)*E_;
  const float* x1 = in + ((size_t)(k*B_) + 1)*E_;
  const float* x2 = in + ((size_t)(k*B_) + 2)*E_;
  const float* x3 = in + ((size_t)(k*B_) + 3)*E_;
  float a0=0.f, a1=0.f, a2=0.f, a3=0.f;
  #pragma unroll
  for (int j = 0; j < 4; j++){
    int e = (j*64 + lane)*4;
    float4 w = *(const float4*)(wrow + e);
    float4 p;
    p = *(const float4*)(x0+e); a0 += w.x*p.x + w.y*p.y + w.z*p.z + w.w*p.w;
    p = *(const float4*)(x1+e); a1 += w.x*p.x + w.y*p.y + w.z*p.z + w.w*p.w;
    p = *(const float4*)(x2+e); a2 += w.x*p.x + w.y*p.y + w.z*p.z + w.w*p.w;
    p = *(const float4*)(x3+e); a3 += w.x*p.x + w.y*p.y + w.z*p.z + w.w*p.w;
  }
  #pragma unroll
  for (int off = 32; off; off >>= 1){
    a0 += __shfl_down(a0, off); a1 += __shfl_down(a1, off);
    a2 += __shfl_down(a2, off); a3 += __shfl_down(a3, off);
  }
  if (lane == 0){
    float bb = bias[k*E_ + f];
    outp[((size_t)(k*B_) + 0)*E_ + f] = a0 + bb;
    outp[((size_t)(k*B_) + 1)*E_ + f] = a1 + bb;
    outp[((size_t)(k*B_) + 2)*E_ + f] = a2 + bb;
    outp[((size_t)(k*B_) + 3)*E_ + f] = a3 + bb;
  }
}

// ---------------- K9: LayerNorm over E, write d_out[b,k,e] ----------------
__global__ __launch_bounds__(256) void k9_ln(const float* __restrict__ outkb,
                                             const float* __restrict__ gamma,
                                             const float* __restrict__ beta,
                                             float* __restrict__ out){
  __shared__ float rs[4], rs2[4];
  int row = blockIdx.x;            // b*K_ + k
  int b = row >> 3, k = row & 7;
  int t = threadIdx.x, wv = t >> 6, lane = t & 63;
  const float* x = outkb + ((size_t)(k*B_) + b)*E_;
  float4 v = *(const float4*)(x + t*4);
  float s  = v.x + v.y + v.z + v.w;
  float s2 = v.x*v.x + v.y*v.y + v.z*v.z + v.w*v.w;
  #pragma unroll
  for (int off = 32; off; off >>= 1){ s += __shfl_down(s, off); s2 += __shfl_down(s2, off); }
  if (lane == 0){ rs[wv] = s; rs2[wv] = s2; }
  __syncthreads();
  float S  = rs[0] + rs[1] + rs[2] + rs[3];
  float S2 = rs2[0] + rs2[1] + rs2[2] + rs2[3];
  float mu = S * (1.0f/E_);
  float var = S2 * (1.0f/E_) - mu*mu;
  float inv = rsqrtf(var + 1e-5f);
  float4 g  = *(const float4*)(gamma + t*4);
  float4 bt = *(const float4*)(beta + t*4);
  float4 o;
  o.x = g.x*(v.x-mu)*inv + bt.x;
  o.y = g.y*(v.y-mu)*inv + bt.y;
  o.z = g.z*(v.z-mu)*inv + bt.z;
  o.w = g.w*(v.w-mu)*inv + bt.w;
  *(float4*)(out + ((size_t)(b*K_) + k)*E_ + t*4) = o;
}

extern "C" void kernel_launch(void* const* d_in, const int* in_sizes, int n_in,
                              void* d_out, int out_size, void* d_ws, size_t ws_size,
                              hipStream_t stream){
  const float* rep     = (const float*)d_in[0];
  const float* mask    = (const float*)d_in[1];
  const float* queries = (const float*)d_in[2];
  const float* Wq = (const float*)d_in[3];
  const float* bq = (const float*)d_in[4];
  const float* Wk = (const float*)d_in[5];
  const float* bk = (const float*)d_in[6];
  const float* Wv = (const float*)d_in[7];
  const float* bv = (const float*)d_in[8];
  const float* Wo = (const float*)d_in[9];
  const float* bo = (const float*)d_in[10];
  const float* Wp = (const float*)d_in[11];
  const float* bp = (const float*)d_in[12];
  const float* gamma = (const float*)d_in[13];
  const float* beta  = (const float*)d_in[14];
  float* out = (float*)d_out;

  char* ws = (char*)d_ws;
  size_t off = 0;
  ushort* repT  = (ushort*)(ws + off); off += (size_t)B_*E_*S_*2;   // 16 MB
  float*  qs    = (float*)(ws + off);  off += (size_t)K_*E_*4;      // 32 KB
  ushort* qkb   = (ushort*)(ws + off); off += (size_t)KH_*E_*2;     // 256 KB
  float*  qb    = (float*)(ws + off);  off += 1024;
  float*  scores= (float*)(ws + off);  off += (size_t)B_*KH_*S_*4;  // 4 MB
  ushort* probs = (ushort*)(ws + off); off += (size_t)B_*KH_*S_*2;  // 2 MB
  float*  wrep  = (float*)(ws + off);  off += (size_t)B_*KH_*E_*4;  // 2 MB
  float*  ctx   = (float*)(ws + off);  off += (size_t)K_*B_*E_*4;
  float*  attn  = (float*)(ws + off);  off += (size_t)K_*B_*E_*4;
  float*  outkb = (float*)(ws + off);  off += (size_t)K_*B_*E_*4;

  t0_repT   <<<2048, 256, 0, stream>>>(rep, repT);
  k1_qs     <<<2048, 256, 0, stream>>>(queries, Wq, bq, qs);
  k2_qk     <<<256,  256, 0, stream>>>(qs, Wk, bk, qkb, qb);
  k3_scores <<<128,  256, 0, stream>>>(rep, qkb, qb, mask, scores);
  k4_softmax<<<512,  256, 0, stream>>>(scores, probs);
  k5_wrep   <<<256,  256, 0, stream>>>(probs, repT, wrep);
  k6_ctx    <<<2048, 256, 0, stream>>>(wrep, Wv, bv, ctx);
  gemv_kb   <<<2048, 256, 0, stream>>>(ctx, Wo, bo, attn);
  gemv_kb   <<<2048, 256, 0, stream>>>(attn, Wp, bp, outkb);
  k9_ln     <<<32,   256, 0, stream>>>(outkb, gamma, beta, out);
}